// Round 3
// baseline (880.608 us; speedup 1.0000x reference)
//
#include <hip/hip_runtime.h>
#include <math.h>

#define EMB 128
#define NR 6
#define NS 7
#define NB 8
#define TL 128   // triplets per block in the MFMA bilinear kernel

typedef __attribute__((ext_vector_type(8))) short short8;   // 8 bf16 = 4 VGPR
typedef __attribute__((ext_vector_type(4))) float floatx4;  // MFMA C/D

__device__ __forceinline__ short f2bf(float f) {  // fp32 -> bf16 RNE
  unsigned int u = __float_as_uint(f);
  u = u + 0x7fff + ((u >> 16) & 1);
  return (short)(u >> 16);
}

// ---------------------------------------------------------------------------
__global__ void zero_kernel(float4* __restrict__ p, long n4) {
  long i = (long)blockIdx.x * blockDim.x + threadIdx.x;
  long stride = (long)gridDim.x * blockDim.x;
  float4 z; z.x = z.y = z.z = z.w = 0.f;
  for (; i < n4; i += stride) p[i] = z;
}

__global__ void izero_kernel(int* __restrict__ p, int n) {
  int i = blockIdx.x * 256 + threadIdx.x;
  if (i < n) p[i] = 0;
}

// W_bilin fp32 -> bf16 (same flat layout [i][j][k])
__global__ void wcvt_kernel(const float* __restrict__ w, short* __restrict__ o,
                            int n) {
  int i = blockIdx.x * 256 + threadIdx.x;
  if (i < n) o[i] = f2bf(w[i]);
}

// ---- dst-binning: histogram -> exclusive scan -> permutation scatter ------
__global__ void hist_kernel(const int* __restrict__ dst, int* __restrict__ cnt,
                            int L) {
  int i = blockIdx.x * 256 + threadIdx.x;
  if (i < L) atomicAdd(&cnt[dst[i]], 1);
}

__global__ __launch_bounds__(1024) void scan_kernel(int* __restrict__ c,
                                                    int E) {
  __shared__ int part[1024];
  const int tid = threadIdx.x;
  const int per = (E + 1023) >> 10;
  int lo = tid * per;
  int hi = lo + per; if (hi > E) hi = E; if (lo > E) lo = E;
  int s = 0;
  for (int i = lo; i < hi; ++i) s += c[i];
  part[tid] = s;
  __syncthreads();
  for (int d = 1; d < 1024; d <<= 1) {
    int v = (tid >= d) ? part[tid - d] : 0;
    __syncthreads();
    part[tid] += v;
    __syncthreads();
  }
  int pre = (tid == 0) ? 0 : part[tid - 1];
  for (int i = lo; i < hi; ++i) { int v = c[i]; c[i] = pre; pre += v; }
}

__global__ void scatter_kernel(const int* __restrict__ dst,
                               int* __restrict__ cur, int* __restrict__ perm,
                               int L) {
  int i = blockIdx.x * 256 + threadIdx.x;
  if (i < L) {
    int p = atomicAdd(&cur[dst[i]], 1);
    perm[p] = i;
  }
}

// ---------------------------------------------------------------------------
// w = (rbf @ W_rbf) * silu(m @ W_m + b_m)        [E, EMB]  (unchanged)
// ---------------------------------------------------------------------------
__global__ __launch_bounds__(256) void edge_w_kernel(
    const float* __restrict__ rbf, const float* __restrict__ m,
    const float* __restrict__ W_rbf, const float* __restrict__ W_m,
    const float* __restrict__ b_m, float* __restrict__ w_out, int E) {
  __shared__ float mrow[EMB];
  __shared__ float rrow[NR];
  __shared__ float pacc[EMB];

  const int tid = threadIdx.x;
  const int i = tid & 127;
  const int h = tid >> 7;

  float Wreg[64];
#pragma unroll
  for (int kk = 0; kk < 64; ++kk) Wreg[kk] = W_m[(h * 64 + kk) * EMB + i];
  float wr[NR];
#pragma unroll
  for (int r = 0; r < NR; ++r) wr[r] = W_rbf[r * EMB + i];
  const float bm = b_m[i];

  for (int e = blockIdx.x; e < E; e += gridDim.x) {
    __syncthreads();
    if (tid < EMB) mrow[tid] = m[(long)e * EMB + tid];
    if (tid < NR) rrow[tid] = rbf[(long)e * NR + tid];
    __syncthreads();

    float acc = 0.f;
    const float4* mv4 = (const float4*)&mrow[h * 64];
#pragma unroll
    for (int q = 0; q < 16; ++q) {
      float4 mv = mv4[q];
      acc += Wreg[q * 4 + 0] * mv.x + Wreg[q * 4 + 1] * mv.y +
             Wreg[q * 4 + 2] * mv.z + Wreg[q * 4 + 3] * mv.w;
    }
    if (h == 1) pacc[i] = acc;
    __syncthreads();
    if (h == 0) {
      float x = acc + pacc[i] + bm;
      float sig = 1.f / (1.f + expf(-x));
      float act = x * sig;
      float ar = 0.f;
#pragma unroll
      for (int r = 0; r < NR; ++r) ar += wr[r] * rrow[r];
      w_out[(long)e * EMB + i] = ar * act;
    }
  }
}

// ---------------------------------------------------------------------------
// MFMA triplet kernel, dst-sorted order (perm), run-merged scatter.
// 128 triplets/block, 512 threads = 8 waves. Wave wv owns M-tiles
// (wv>>2)*4..+3 and N-tiles (wv&3)*2..+1. A-fragments in registers across the
// j-loop. After the j-loop, accumulators round-trip through LDS (overlaying
// the staging buffers, padded stride 132 -> conflict-free) and a run-length
// merge over equal consecutive dst emits one atomic per run.
// ---------------------------------------------------------------------------
template <bool WB>
__global__ __launch_bounds__(512, 2) void triplet_mfma(
    const float* __restrict__ rbf, const float* __restrict__ m,
    const float* __restrict__ o, const int* __restrict__ lg_src,
    const int* __restrict__ lg_dst, const float* __restrict__ W_sbf,
    const float* __restrict__ W_bilin_f, const short* __restrict__ W_bilin_h,
    const int* __restrict__ perm, float* __restrict__ m_update, int L) {
  // 67584 B: [0,32K) aS A-frags, [32K,64K) wS B-frags; after the j-loop the
  // whole region is reused as xS[128][132] fp32.
  __shared__ __align__(16) char smem[67584];
  short* aS = (short*)smem;
  short* wS = (short*)(smem + 32768);
  float* xS = (float*)smem;
  __shared__ float sS[TL * 9];  // sbf, padded stride 9
  __shared__ int srcS[TL];
  __shared__ int dstS[TL];      // -1 for pad rows

  const int tid = threadIdx.x;
  const int lane = tid & 63;
  const int wv = tid >> 6;
  const long base = (long)blockIdx.x * TL;

  if (tid < TL) {
    long l = base + tid;
    int lc = (l < L) ? (int)l : 0;
    int id = perm ? perm[lc] : lc;
    srcS[tid] = lg_src[id];
    dstS[tid] = (l < L) ? lg_dst[id] : -1;
  }
  __syncthreads();

  // ---- stage A: gather m rows (fp32), convert to bf16, fragment order ----
#pragma unroll
  for (int iter = 0; iter < 4; ++iter) {
    int s = iter * 512 + tid;             // slot 0..2047
    int c = s >> 6, l2 = s & 63;
    int mt = c >> 2, ks = c & 3;
    int row = mt * 16 + (l2 & 15);
    int k = ks * 32 + (l2 >> 4) * 8;
    const float* src = m + (long)srcS[row] * EMB + k;
    float4 v0 = *(const float4*)src;
    float4 v1 = *(const float4*)(src + 4);
    short8 h;
    h[0] = f2bf(v0.x); h[1] = f2bf(v0.y); h[2] = f2bf(v0.z); h[3] = f2bf(v0.w);
    h[4] = f2bf(v1.x); h[5] = f2bf(v1.y); h[6] = f2bf(v1.z); h[7] = f2bf(v1.w);
    *(short8*)&aS[s * 8] = h;
  }

  // ---- sbf per triplet (threads 0..127), fp32 ----
  if (tid < TL) {
    int src = srcS[tid];
    int de = dstS[tid];
    if (de < 0) de = src;  // pad rows: any valid edge (result discarded)
    float r1x = o[src * 3 + 0], r1y = o[src * 3 + 1], r1z = o[src * 3 + 2];
    float r2x = o[de * 3 + 0], r2y = o[de * 3 + 1], r2z = o[de * 3 + 2];
    float dotv = r1x * r2x + r1y * r2y + r1z * r2z;
    float cx = r1y * r2z - r1z * r2y;
    float cy = r1z * r2x - r1x * r2z;
    float cz = r1x * r2y - r1y * r2x;
    float crs = sqrtf(cx * cx + cy * cy + cz * cz);
    float angle = atan2f(crs, dotv);
    float cbf[NS];
#pragma unroll
    for (int s_ = 0; s_ < NS; ++s_) cbf[s_] = cosf(angle * (float)s_);
    float rb[NR];
#pragma unroll
    for (int r = 0; r < NR; ++r) rb[r] = rbf[src * NR + r];
#pragma unroll
    for (int b = 0; b < NB; ++b) {
      float sb = 0.f;
#pragma unroll
      for (int s_ = 0; s_ < NS; ++s_) {
        float t = 0.f;
#pragma unroll
        for (int r = 0; r < NR; ++r)
          t += rb[r] * W_sbf[(s_ * NR + r) * NB + b];
        sb += cbf[s_] * t;
      }
      sS[tid * 9 + b] = sb;
    }
  }
  __syncthreads();

  // ---- load j-invariant A fragments into registers ----
  const int mh = wv >> 2;        // M-half
  const int n0 = (wv & 3) * 2;   // first N-tile
  short8 A[4][4];
#pragma unroll
  for (int mt = 0; mt < 4; ++mt)
#pragma unroll
    for (int ks = 0; ks < 4; ++ks)
      A[mt][ks] = *(const short8*)&aS[(((mh * 4 + mt) * 4 + ks) * 64 + lane) * 8];

  float accf[4][2][4];
#pragma unroll
  for (int mt = 0; mt < 4; ++mt)
#pragma unroll
    for (int nn = 0; nn < 2; ++nn)
#pragma unroll
      for (int r = 0; r < 4; ++r) accf[mt][nn][r] = 0.f;

  const int kq = lane >> 4;

#pragma unroll 1
  for (int j = 0; j < NB; ++j) {
    __syncthreads();  // previous wS fully consumed
    // ---- stage B: W_bilin[:, j, :] as bf16 fragments ----
#pragma unroll
    for (int iter = 0; iter < 4; ++iter) {
      int s = iter * 512 + tid;           // slot 0..2047
      int c2 = s >> 6, l2 = s & 63;
      int ks = c2 >> 3, nt = c2 & 7;
      int i = nt * 16 + (l2 & 15);
      int k = ks * 32 + (l2 >> 4) * 8;
      short8 h;
      if (WB) {
        h = *(const short8*)&W_bilin_h[((long)i * NB + j) * EMB + k];
      } else {
        const float* src = W_bilin_f + ((long)i * NB + j) * EMB + k;
        float4 v0 = *(const float4*)src;
        float4 v1 = *(const float4*)(src + 4);
        h[0] = f2bf(v0.x); h[1] = f2bf(v0.y);
        h[2] = f2bf(v0.z); h[3] = f2bf(v0.w);
        h[4] = f2bf(v1.x); h[5] = f2bf(v1.y);
        h[6] = f2bf(v1.z); h[7] = f2bf(v1.w);
      }
      *(short8*)&wS[s * 8] = h;
    }
    __syncthreads();

    floatx4 C[4][2];
#pragma unroll
    for (int mt = 0; mt < 4; ++mt)
#pragma unroll
      for (int nn = 0; nn < 2; ++nn) C[mt][nn] = (floatx4)0.f;

#pragma unroll
    for (int ks = 0; ks < 4; ++ks) {
      short8 b0 = *(const short8*)&wS[((ks * 8 + n0) * 64 + lane) * 8];
      short8 b1 = *(const short8*)&wS[((ks * 8 + n0 + 1) * 64 + lane) * 8];
#pragma unroll
      for (int mt = 0; mt < 4; ++mt) {
        C[mt][0] = __builtin_amdgcn_mfma_f32_16x16x32_bf16(A[mt][ks], b0,
                                                           C[mt][0], 0, 0, 0);
        C[mt][1] = __builtin_amdgcn_mfma_f32_16x16x32_bf16(A[mt][ks], b1,
                                                           C[mt][1], 0, 0, 0);
      }
    }

    // fp32 scale by sbf[l, j], accumulate
#pragma unroll
    for (int mt = 0; mt < 4; ++mt) {
#pragma unroll
      for (int r = 0; r < 4; ++r) {
        float s_ = sS[((mh * 4 + mt) * 16 + kq * 4 + r) * 9 + j];
        accf[mt][0][r] += s_ * C[mt][0][r];
        accf[mt][1][r] += s_ * C[mt][1][r];
      }
    }
  }

  // ---- dump accumulators to LDS (xS overlays aS/wS) ----
  __syncthreads();  // all waves done with aS/wS/sS reads
  const int col16 = lane & 15;
#pragma unroll
  for (int mt = 0; mt < 4; ++mt) {
#pragma unroll
    for (int nn = 0; nn < 2; ++nn) {
#pragma unroll
      for (int r = 0; r < 4; ++r) {
        int row = (mh * 4 + mt) * 16 + kq * 4 + r;
        int c = (n0 + nn) * 16 + col16;
        xS[row * 132 + c] = accf[mt][nn][r];
      }
    }
  }
  __syncthreads();

  // ---- run-merged scatter: one atomic per (run of equal dst) x column ----
  {
    const int c = tid & 127;
    const int chunk = tid >> 7;   // 4 chunks x 32 rows
    const int r0 = chunk * 32;
    float run = 0.f;
    int cur = dstS[r0];
#pragma unroll 1
    for (int r = r0; r < r0 + 32; ++r) {
      int d = dstS[r];
      float v = xS[r * 132 + c];
      if (d != cur) {
        if (cur >= 0) unsafeAtomicAdd(m_update + (long)cur * EMB + c, run);
        run = 0.f;
        cur = d;
      }
      run += v;
    }
    if (cur >= 0) unsafeAtomicAdd(m_update + (long)cur * EMB + c, run);
  }
}

// ---------------------------------------------------------------------------
extern "C" void kernel_launch(void* const* d_in, const int* in_sizes, int n_in,
                              void* d_out, int out_size, void* d_ws,
                              size_t ws_size, hipStream_t stream) {
  const float* rbf = (const float*)d_in[0];
  const float* m = (const float*)d_in[1];
  const float* o = (const float*)d_in[2];
  const int* lg_src = (const int*)d_in[3];
  const int* lg_dst = (const int*)d_in[4];
  const float* W_rbf = (const float*)d_in[5];
  const float* W_m = (const float*)d_in[6];
  const float* b_m = (const float*)d_in[7];
  const float* W_sbf = (const float*)d_in[8];
  const float* W_bilin = (const float*)d_in[9];

  const int E = in_sizes[1] / EMB;
  const int L = in_sizes[3];

  float* w_out = (float*)d_out;
  float* m_update = (float*)d_out + (long)E * EMB;

  long n4 = (long)E * EMB / 4;
  zero_kernel<<<1024, 256, 0, stream>>>((float4*)m_update, n4);
  edge_w_kernel<<<2048, 256, 0, stream>>>(rbf, m, W_rbf, W_m, b_m, w_out, E);

  const int wn = EMB * NB * EMB;  // 131072 bf16 elements
  size_t idx_bytes = ((size_t)E + (size_t)L) * sizeof(int);
  size_t w_off = (idx_bytes + 15) & ~(size_t)15;
  size_t need_full = w_off + (size_t)wn * sizeof(short);
  int nblk = (L + TL - 1) / TL;

  if (ws_size >= need_full) {
    int* cursor = (int*)d_ws;
    int* perm = cursor + E;
    short* wh = (short*)((char*)d_ws + w_off);
    izero_kernel<<<(E + 255) / 256, 256, 0, stream>>>(cursor, E);
    wcvt_kernel<<<(wn + 255) / 256, 256, 0, stream>>>(W_bilin, wh, wn);
    hist_kernel<<<(L + 255) / 256, 256, 0, stream>>>(lg_dst, cursor, L);
    scan_kernel<<<1, 1024, 0, stream>>>(cursor, E);
    scatter_kernel<<<(L + 255) / 256, 256, 0, stream>>>(lg_dst, cursor, perm,
                                                        L);
    triplet_mfma<true><<<nblk, 512, 0, stream>>>(
        rbf, m, o, lg_src, lg_dst, W_sbf, nullptr, wh, perm, m_update, L);
  } else if (ws_size >= (size_t)wn * sizeof(short)) {
    short* wh = (short*)d_ws;
    wcvt_kernel<<<(wn + 255) / 256, 256, 0, stream>>>(W_bilin, wh, wn);
    triplet_mfma<true><<<nblk, 512, 0, stream>>>(
        rbf, m, o, lg_src, lg_dst, W_sbf, nullptr, wh, nullptr, m_update, L);
  } else {
    triplet_mfma<false><<<nblk, 512, 0, stream>>>(
        rbf, m, o, lg_src, lg_dst, W_sbf, W_bilin, nullptr, nullptr, m_update,
        L);
  }
}